// Round 1
// 335.213 us; speedup vs baseline: 1.1674x; 1.1674x over previous
//
#include <hip/hip_runtime.h>
#include <math.h>

#define BB 4
#define CC 128
#define BT 32
#define NBOX 4
#define HH 256
#define WW 256
#define HW (HH*WW)
#define SP 257
#define SPLANE (SP*SP)
#define NPLANE (BB*BT)          // 128 integral-image planes
#define CHUNK 32                // rows per column-scan chunk
#define NCHUNK (HH/CHUNK)       // 8
#define ROWS 8                  // output rows per box_sample block

// ---------------- Kernel A: 1x1 conv (128->32) + BN1 + row inclusive scan ----------------
// Block = one image row (b,i): 256 threads, one pixel each, 32 channels in registers.
// The row prefix-scan (formerly a separate 67MB-traffic pass) is done in-register:
// per-wave shfl scan + cross-wave offsets via 384B LDS.
__global__ __launch_bounds__(256) void conv_bn1_scan(
        const float* __restrict__ x, const float* __restrict__ w1,
        const float* __restrict__ g1, const float* __restrict__ b1,
        const float* __restrict__ m1, const float* __restrict__ v1,
        float* __restrict__ t) {
    int pix = blockIdx.x * 256 + threadIdx.x;   // over B*HW
    int b  = pix >> 16;
    int ij = pix & 65535;
    const float* xb = x + b * (CC * HW) + ij;
    float acc[BT];
    #pragma unroll
    for (int k = 0; k < BT; ++k) acc[k] = 0.f;
    #pragma unroll 4
    for (int c = 0; c < CC; ++c) {
        float xv = xb[c * HW];
        #pragma unroll
        for (int k = 0; k < BT; ++k)
            acc[k] = fmaf(xv, w1[k * CC + c], acc[k]);
    }
    // BN1 (must precede the scan: reference scans bn1(conv) output)
    #pragma unroll
    for (int k = 0; k < BT; ++k) {
        float inv = g1[k] * __frsqrt_rn(v1[k] + 1e-5f);
        acc[k] = acc[k] * inv + (b1[k] - m1[k] * inv);
    }
    int lane = threadIdx.x & 63;
    int wave = threadIdx.x >> 6;
    // inclusive scan across 256 threads, all 32 channels in flight (step-outer for ILP)
    #pragma unroll
    for (int off = 1; off < 64; off <<= 1) {
        bool p = lane >= off;
        #pragma unroll
        for (int k = 0; k < BT; ++k) {
            float o = __shfl_up(acc[k], off, 64);
            if (p) acc[k] += o;
        }
    }
    __shared__ float wtot[3][BT];
    if (lane == 63 && wave < 3) {
        #pragma unroll
        for (int k = 0; k < BT; ++k) wtot[wave][k] = acc[k];
    }
    __syncthreads();
    float* tb = t + b * (BT * HW) + ij;
    #pragma unroll
    for (int k = 0; k < BT; ++k) {
        float off = 0.f;
        if (wave > 0) off += wtot[0][k];
        if (wave > 1) off += wtot[1][k];
        if (wave > 2) off += wtot[2][k];
        tb[k * HW] = acc[k] + off;
    }
}

// ---------------- Kernel B2a: per-chunk column partial sums ----------------
// grid = NPLANE*NCHUNK blocks of 256; thread = column j.
__global__ __launch_bounds__(256) void col_partial(const float* __restrict__ t,
                                                   float* __restrict__ T) {
    int plane = blockIdx.x >> 3;
    int chunk = blockIdx.x & 7;
    int j = threadIdx.x;
    const float* tp = t + (size_t)plane * HW + chunk * CHUNK * WW + j;
    float s = 0.f;
    #pragma unroll 8
    for (int r = 0; r < CHUNK; ++r) s += tp[r * WW];
    T[blockIdx.x * 256 + j] = s;
}

// ---------------- Kernel B2b: column scan with chunk offsets -> padded S ----------------
__global__ __launch_bounds__(256) void col_final(const float* __restrict__ t,
                                                 const float* __restrict__ T,
                                                 float* __restrict__ s) {
    int plane = blockIdx.x >> 3;
    int chunk = blockIdx.x & 7;
    int j = threadIdx.x;
    float off = 0.f;
    for (int c = 0; c < chunk; ++c) off += T[(plane * 8 + c) * 256 + j];
    const float* tp = t + (size_t)plane * HW + chunk * CHUNK * WW + j;
    float* sp = s + (size_t)plane * SPLANE;
    if (chunk == 0) {                    // top padding row
        sp[j + 1] = 0.f;
        if (j == 0) sp[0] = 0.f;
    }
    float run = off;
    int rowbase = chunk * CHUNK;
    #pragma unroll 4
    for (int r = 0; r < CHUNK; ++r) {
        run += tp[r * WW];
        sp[(size_t)(rowbase + r + 1) * SP + j + 1] = run;
        if (j == 0) sp[(size_t)(rowbase + r + 1) * SP] = 0.f;   // left padding col
    }
}

// ---------------- Kernel C: box sample via shared D-rows + BN2 + relus ----------------
// grid = B*BT*NBOX*(H/ROWS) blocks; each block produces ROWS=8 output rows.
// Each wave builds 2 D-rows into LDS; after one barrier every thread emits 8
// elements at column j, amortizing horizontal setup + BN2 scalars 8x.
__global__ __launch_bounds__(256) void box_sample(
        const float* __restrict__ s, const float* __restrict__ x,
        const float* __restrict__ xmin, const float* __restrict__ xmax,
        const float* __restrict__ ymin, const float* __restrict__ ymax,
        const float* __restrict__ g2, const float* __restrict__ b2,
        const float* __restrict__ m2, const float* __restrict__ v2,
        float* __restrict__ out) {
    __shared__ float D[ROWS][SP];
    int bid = blockIdx.x;
    int ig = bid & 31;                   // H/ROWS = 32 row-groups
    int n  = (bid >> 5) & 3;
    int k  = (bid >> 7) & 31;
    int b  = bid >> 12;
    int j  = threadIdx.x;
    int lane = j & 63;
    int wave = j >> 6;
    int kn = k * NBOX + n;
    int ibase = ig * ROWS;
    const float* sp = s + (size_t)(b * BT + k) * SPLANE;

    float xmn = xmin[kn], xmx = xmax[kn], ymn = ymin[kn], ymx = ymax[kn];

    // Each wave builds D rows {wave, wave+4}: D[r][v] = rowHi(v) - rowLo(v)
    #pragma unroll
    for (int rr = 0; rr < 2; ++rr) {
        int r = wave + rr * 4;
        float fi = (float)(ibase + r);
        float u_hi = fminf(fmaxf(fi + xmx, 0.f), 256.f);
        float u_lo = fminf(fmaxf(fi + xmn, 0.f), 256.f);
        int i1 = (int)fminf(floorf(u_hi), 255.f);
        int i0 = (int)fminf(floorf(u_lo), 255.f);
        float wu1 = u_hi - (float)i1;
        float wu0 = u_lo - (float)i0;
        const float* rA = sp + (size_t)i1 * SP;
        const float* rB = rA + SP;
        const float* rC = sp + (size_t)i0 * SP;
        const float* rD = rC + SP;
        #pragma unroll
        for (int tcol = 0; tcol < 4; ++tcol) {
            int c = lane + tcol * 64;
            D[r][c] = rA[c] * (1.f - wu1) + rB[c] * wu1
                    - rC[c] * (1.f - wu0) - rD[c] * wu0;
        }
        if (lane == 0) {
            int c = 256;
            D[r][c] = rA[c] * (1.f - wu1) + rB[c] * wu1
                    - rC[c] * (1.f - wu0) - rD[c] * wu0;
        }
    }
    __syncthreads();

    // horizontal setup: once per thread, reused for all 8 rows
    float v_hi = fminf(fmaxf((float)j + ymx, 0.f), 256.f);
    float v_lo = fminf(fmaxf((float)j + ymn, 0.f), 256.f);
    int j1 = (int)fminf(floorf(v_hi), 255.f);
    int j0 = (int)fminf(floorf(v_lo), 255.f);
    float wv1 = v_hi - (float)j1;
    float wv0 = v_lo - (float)j0;
    float cv1 = 1.f - wv1;
    float cv0 = 1.f - wv0;

    float inv = g2[kn] * __frsqrt_rn(v2[kn] + 1e-3f);
    float scale = inv * __frcp_rn((xmx - xmn) * (ymx - ymn));
    float add = b2[kn] - m2[kn] * inv;

    int obase = ((b * CC + kn) * HH + ibase) * WW + j;   // < 2^25, fits int
    const float* xp = x + obase;
    float* op = out + obase;
    #pragma unroll
    for (int r = 0; r < ROWS; ++r) {
        float hi = D[r][j1] * cv1 + D[r][j1 + 1] * wv1;
        float lo = D[r][j0] * cv0 + D[r][j0 + 1] * wv0;
        float val = (hi - lo) * scale + add;
        val = fmaxf(val, 0.f);                            // relu(bn2)
        float xv = __builtin_nontemporal_load(xp + r * WW);
        __builtin_nontemporal_store(fmaxf(xv + val, 0.f), op + r * WW);
    }
}

extern "C" void kernel_launch(void* const* d_in, const int* in_sizes, int n_in,
                              void* d_out, int out_size, void* d_ws, size_t ws_size,
                              hipStream_t stream) {
    const float* x    = (const float*)d_in[0];
    const float* w1   = (const float*)d_in[1];
    const float* g1   = (const float*)d_in[2];
    const float* b1   = (const float*)d_in[3];
    const float* m1   = (const float*)d_in[4];
    const float* v1   = (const float*)d_in[5];
    const float* xmin = (const float*)d_in[6];
    const float* xmax = (const float*)d_in[7];
    const float* ymin = (const float*)d_in[8];
    const float* ymax = (const float*)d_in[9];
    const float* g2   = (const float*)d_in[10];
    const float* b2   = (const float*)d_in[11];
    const float* m2   = (const float*)d_in[12];
    const float* v2   = (const float*)d_in[13];
    float* out = (float*)d_out;

    float* h = (float*)d_ws;                        // B*BT*HW floats (33.5 MB), row-scanned
    float* S = h + (size_t)BB * BT * HW;            // NPLANE*SPLANE floats (33.8 MB)
    float* T = S + (size_t)NPLANE * SPLANE;         // NPLANE*NCHUNK*256 floats (1 MB)

    conv_bn1_scan<<<(BB * HW) / 256, 256, 0, stream>>>(x, w1, g1, b1, m1, v1, h);
    col_partial  <<<NPLANE * NCHUNK, 256, 0, stream>>>(h, T);
    col_final    <<<NPLANE * NCHUNK, 256, 0, stream>>>(h, T, S);
    box_sample   <<<BB * BT * NBOX * (HH / ROWS), 256, 0, stream>>>(
                     S, x, xmin, xmax, ymin, ymax, g2, b2, m2, v2, out);
}